// Round 1
// baseline (270.369 us; speedup 1.0000x reference)
//
#include <hip/hip_runtime.h>

// Problem: Length_Regulate alignment matrix.
//   repeats = (int)(durations + 0.5)            [B, T]  (durations >= 1 => repeats >= 1)
//   ends    = cumsum(repeats, axis=1)
//   starts  = ends - repeats  (== shifted ends, contiguous intervals)
//   out[b, t, j] = 1.0f iff starts[j] <= t < ends[j], else 0.0f
// Output [B, max_len, T] float32 = 268 MB; one-hot per (b,t) row -> write-bound.

#define T_TEXT 512
#define ROWS 8          // output rows (t values) per block
#define WBLOCK 256      // writer block size

// ---- Kernel 1: per-batch inclusive scan of rounded durations -> ends ----
__global__ void lr_scan_kernel(const float* __restrict__ dur,
                               int* __restrict__ ends) {
    __shared__ int s[T_TEXT];
    const int b = blockIdx.x;
    const int tid = threadIdx.x;          // blockDim.x == 512
    float d = dur[b * T_TEXT + tid];
    s[tid] = (int)(d + 0.5f);             // same FP op sequence as reference
    __syncthreads();
    // Hillis-Steele inclusive scan (read-before-write with barrier)
    for (int off = 1; off < T_TEXT; off <<= 1) {
        int v = s[tid];
        int add = (tid >= off) ? s[tid - off] : 0;
        __syncthreads();
        s[tid] = v + add;
        __syncthreads();
    }
    ends[b * T_TEXT + tid] = s[tid];
}

// ---- Kernel 2: stream one-hot rows out, fully coalesced float4 stores ----
__global__ __launch_bounds__(WBLOCK) void lr_write_kernel(
        const int* __restrict__ ends_all,
        float* __restrict__ out,
        int max_len) {
    __shared__ int s_ends[T_TEXT];
    __shared__ int s_j[ROWS];

    const int b  = blockIdx.y;
    const int t0 = blockIdx.x * ROWS;
    const int tid = threadIdx.x;

    // Stage this batch's cumsum (2 KB) into LDS; source is 64 KB, L2-resident.
    const int* ends = ends_all + b * T_TEXT;
    s_ends[tid]       = ends[tid];
    s_ends[tid + 256] = ends[tid + 256];
    __syncthreads();

    // One binary search per row: first j with ends[j] > t (contiguous
    // intervals => starts[j] <= t automatically holds for that j).
    if (tid < ROWS) {
        int t = t0 + tid;
        int j = -1;
        if (t < s_ends[T_TEXT - 1]) {
            int lo = 0, hi = T_TEXT;
            while (lo < hi) {
                int mid = (lo + hi) >> 1;
                if (s_ends[mid] > t) hi = mid; else lo = mid + 1;
            }
            j = lo;
        }
        s_j[tid] = j;
    }
    __syncthreads();

    // ROWS * 512 floats = ROWS*128 float4, rows contiguous in memory ->
    // flat float4 index f covers the whole block tile coalesced.
    float4* outv = (float4*)(out + ((size_t)b * max_len + t0) * T_TEXT);
    const int nvec = ROWS * (T_TEXT / 4);     // 1024
    for (int f = tid; f < nvec; f += WBLOCK) {
        int r = f >> 7;               // row within tile
        int c = (f & 127) << 2;       // starting column
        int j = s_j[r];
        float4 v = make_float4(0.f, 0.f, 0.f, 0.f);
        int k = j - c;
        if ((unsigned)k < 4u) ((float*)&v)[k] = 1.0f;
        if (t0 + r < max_len) outv[f] = v;
    }
}

extern "C" void kernel_launch(void* const* d_in, const int* in_sizes, int n_in,
                              void* d_out, int out_size, void* d_ws, size_t ws_size,
                              hipStream_t stream) {
    const float* dur = (const float*)d_in[0];
    float* out = (float*)d_out;

    const int BT = in_sizes[0];           // B * T_TEXT (= 16384)
    const int B = BT / T_TEXT;            // 32
    const int max_len = out_size / BT;    // 4096

    int* ends = (int*)d_ws;               // B*T_TEXT int32 = 64 KB scratch

    lr_scan_kernel<<<B, T_TEXT, 0, stream>>>(dur, ends);

    dim3 grid((max_len + ROWS - 1) / ROWS, B);
    lr_write_kernel<<<grid, WBLOCK, 0, stream>>>(ends, out, max_len);
}